// Round 1
// baseline (722.659 us; speedup 1.0000x reference)
//
#include <hip/hip_runtime.h>
#include <math.h>

#define NN 100000
#define NE 1600000
#define F_IN 128
#define C 128           // N_HEADS * F_OUT
#define NEG_SLOPE 0.2f

// ---------------------------------------------------------------------------
// proj: x = feat @ W  (to ws), res = feat @ W_res (to d_out),
//       a_s[n,h] = sum_f x[n,h,f]*att_src[h,f], a_d likewise.
// Block = 128 threads handles 8 nodes. feat rows staged in LDS (broadcast
// reads). W streamed coalesced (L2-resident, 64 KB each).
// ---------------------------------------------------------------------------
__global__ __launch_bounds__(128)
void proj_kernel(const float* __restrict__ feat,
                 const float* __restrict__ W,
                 const float* __restrict__ Wr,
                 const float* __restrict__ att_src,
                 const float* __restrict__ att_dst,
                 float* __restrict__ x,
                 float* __restrict__ a_s,
                 float* __restrict__ a_d,
                 float* __restrict__ out)
{
    __shared__ float fs[8][F_IN];
    const int t = threadIdx.x;
    const int base = blockIdx.x * 8;

    #pragma unroll
    for (int j = 0; j < 8; ++j) {
        int n = base + j;
        if (n < NN) fs[j][t] = feat[(size_t)n * F_IN + t];
    }
    __syncthreads();

    float acc[8]  = {0.f,0.f,0.f,0.f,0.f,0.f,0.f,0.f};
    float accR[8] = {0.f,0.f,0.f,0.f,0.f,0.f,0.f,0.f};

    #pragma unroll 4
    for (int k = 0; k < F_IN; ++k) {
        float w  = W [k * C + t];
        float wr = Wr[k * C + t];
        #pragma unroll
        for (int j = 0; j < 8; ++j) {
            acc[j]  = fmaf(fs[j][k], w,  acc[j]);
            accR[j] = fmaf(fs[j][k], wr, accR[j]);
        }
    }

    // att_src is [H=4][Fo=32] flat == channel index t  (h = t>>5, f = t&31)
    const int h = t >> 5;
    const float as_w = att_src[t];
    const float ad_w = att_dst[t];

    #pragma unroll
    for (int j = 0; j < 8; ++j) {
        int n = base + j;
        if (n >= NN) break;
        x[(size_t)n * C + t]   = acc[j];
        out[(size_t)n * C + t] = accR[j];   // residual; agg adds on top
        float ps = acc[j] * as_w;
        float pd = acc[j] * ad_w;
        #pragma unroll
        for (int d = 16; d > 0; d >>= 1) {
            ps += __shfl_down(ps, d, 32);
            pd += __shfl_down(pd, d, 32);
        }
        if ((t & 31) == 0) {
            a_s[n * 4 + h] = ps;
            a_d[n * 4 + h] = pd;
        }
    }
}

// ---------------------------------------------------------------------------
// histogram of in-degrees
// ---------------------------------------------------------------------------
__global__ void hist_kernel(const int* __restrict__ dst, int* __restrict__ deg)
{
    int e = blockIdx.x * blockDim.x + threadIdx.x;
    if (e < NE) atomicAdd(&deg[dst[e]], 1);
}

// ---------------------------------------------------------------------------
// single-block exclusive scan of deg -> row_ptr (and a second copy: cursor)
// wave-shuffle scan within 64-lane waves, serial combine of 16 wave sums.
// ---------------------------------------------------------------------------
__global__ __launch_bounds__(1024)
void scan_kernel(const int* __restrict__ deg,
                 int* __restrict__ row_ptr,
                 int* __restrict__ cursor)
{
    __shared__ int wsum[16];
    __shared__ int s_carry;
    const int t = threadIdx.x;
    const int lane = t & 63;
    const int wid  = t >> 6;
    if (t == 0) s_carry = 0;
    __syncthreads();

    for (int base = 0; base < NN; base += 1024) {
        int i = base + t;
        int v0 = (i < NN) ? deg[i] : 0;
        int v = v0;
        #pragma unroll
        for (int off = 1; off < 64; off <<= 1) {
            int u = __shfl_up(v, off, 64);
            if (lane >= off) v += u;
        }
        if (lane == 63) wsum[wid] = v;
        __syncthreads();
        if (t == 0) {
            int run = 0;
            #pragma unroll
            for (int w = 0; w < 16; ++w) { int tmp = wsum[w]; wsum[w] = run; run += tmp; }
        }
        __syncthreads();
        int carry = s_carry;
        int excl = carry + wsum[wid] + (v - v0);
        if (i < NN) { row_ptr[i] = excl; cursor[i] = excl; }
        __syncthreads();
        if (t == 1023) s_carry = carry + wsum[15] + v;
        __syncthreads();
    }
    if (t == 0) row_ptr[NN] = s_carry;   // == NE
}

// ---------------------------------------------------------------------------
// scatter edges into CSR slots (store src node id per slot)
// ---------------------------------------------------------------------------
__global__ void scatter_kernel(const int* __restrict__ src,
                               const int* __restrict__ dst,
                               int* __restrict__ cursor,
                               int* __restrict__ csr_src)
{
    int e = blockIdx.x * blockDim.x + threadIdx.x;
    if (e < NE) {
        int d = dst[e];
        int pos = atomicAdd(&cursor[d], 1);
        csr_src[pos] = src[e];
    }
}

// ---------------------------------------------------------------------------
// aggregation: one 128-thread block per dst node. Softmax over its in-edges
// (per head, 32-lane shuffle reductions), then feature accumulation with
// coalesced x[src] row reads. out += acc (residual already in out).
// ---------------------------------------------------------------------------
__global__ __launch_bounds__(128)
void agg_kernel(const float* __restrict__ x,
                const float* __restrict__ a_s,
                const float* __restrict__ a_d,
                const int* __restrict__ row_ptr,
                const int* __restrict__ csr_src,
                float* __restrict__ out)
{
    __shared__ int   s_src[32];
    __shared__ float s_alpha[32 * 4];
    const int n = blockIdx.x;
    const int t = threadIdx.x;
    const int h = t >> 5;     // head for both channel t and lane-group
    const int l = t & 31;
    const int r0  = row_ptr[n];
    const int deg = row_ptr[n + 1] - r0;
    if (deg == 0) return;     // out keeps the residual

    const float adn = a_d[n * 4 + h];

    // pass 1: per-head max over in-edges
    float m = -1e30f;
    for (int i = l; i < deg; i += 32) {
        int s = csr_src[r0 + i];
        float e = a_s[s * 4 + h] + adn;
        e = (e > 0.f) ? e : NEG_SLOPE * e;
        m = fmaxf(m, e);
    }
    #pragma unroll
    for (int d = 16; d > 0; d >>= 1) m = fmaxf(m, __shfl_down(m, d, 32));
    m = __shfl(m, 0, 32);

    // pass 2: denom
    float ssum = 0.f;
    for (int i = l; i < deg; i += 32) {
        int s = csr_src[r0 + i];
        float e = a_s[s * 4 + h] + adn;
        e = (e > 0.f) ? e : NEG_SLOPE * e;
        ssum += __expf(e - m);
    }
    #pragma unroll
    for (int d = 16; d > 0; d >>= 1) ssum += __shfl_down(ssum, d, 32);
    ssum = __shfl(ssum, 0, 32);
    const float inv = 1.f / ssum;

    // pass 3: weighted feature accumulation, chunked through LDS
    float acc = 0.f;
    for (int c0 = 0; c0 < deg; c0 += 32) {
        int cn = min(32, deg - c0);
        __syncthreads();
        if (t < cn) s_src[t] = csr_src[r0 + c0 + t];
        __syncthreads();
        if (l < cn) {
            int s = s_src[l];
            float e = a_s[s * 4 + h] + adn;
            e = (e > 0.f) ? e : NEG_SLOPE * e;
            s_alpha[l * 4 + h] = __expf(e - m) * inv;
        }
        __syncthreads();
        for (int i = 0; i < cn; ++i) {
            // s_alpha[i*4+h]: 2 broadcast addresses per wave (free);
            // x row read coalesced 512 B
            acc = fmaf(s_alpha[i * 4 + h], x[(size_t)s_src[i] * C + t], acc);
        }
    }
    out[(size_t)n * C + t] += acc;
}

// ---------------------------------------------------------------------------
extern "C" void kernel_launch(void* const* d_in, const int* in_sizes, int n_in,
                              void* d_out, int out_size, void* d_ws, size_t ws_size,
                              hipStream_t stream)
{
    const float* feat    = (const float*)d_in[0];
    const float* W       = (const float*)d_in[1];
    const float* att_src = (const float*)d_in[2];
    const float* att_dst = (const float*)d_in[3];
    const float* W_res   = (const float*)d_in[4];
    const int*   src     = (const int*)d_in[5];
    const int*   dst     = (const int*)d_in[6];
    float* out = (float*)d_out;

    // workspace carve-up
    char* p = (char*)d_ws;
    float* x    = (float*)p;  p += (size_t)NN * C * sizeof(float);   // 51.2 MB
    float* a_s  = (float*)p;  p += (size_t)NN * 4 * sizeof(float);
    float* a_d  = (float*)p;  p += (size_t)NN * 4 * sizeof(float);
    int* deg     = (int*)p;   p += (size_t)NN * sizeof(int);
    int* row_ptr = (int*)p;   p += (size_t)(NN + 1) * sizeof(int);
    int* cursor  = (int*)p;   p += (size_t)NN * sizeof(int);
    int* csr_src = (int*)p;   p += (size_t)NE * sizeof(int);

    hipMemsetAsync(deg, 0, (size_t)NN * sizeof(int), stream);

    proj_kernel<<<NN / 8, 128, 0, stream>>>(feat, W, W_res, att_src, att_dst,
                                            x, a_s, a_d, out);
    hist_kernel<<<(NE + 255) / 256, 256, 0, stream>>>(dst, deg);
    scan_kernel<<<1, 1024, 0, stream>>>(deg, row_ptr, cursor);
    scatter_kernel<<<(NE + 255) / 256, 256, 0, stream>>>(src, dst, cursor, csr_src);
    agg_kernel<<<NN, 128, 0, stream>>>(x, a_s, a_d, row_ptr, csr_src, out);
}

// Round 2
// 631.356 us; speedup vs baseline: 1.1446x; 1.1446x over previous
//
#include <hip/hip_runtime.h>
#include <math.h>

#define NN 100000
#define NE 1600000
#define F_IN 128
#define C 128           // N_HEADS * F_OUT
#define NEG_SLOPE 0.2f
#define SCAN_NB ((NN + 1023) / 1024)   // 98

typedef __attribute__((ext_vector_type(8))) short short8;   // 8 x bf16 (4 VGPRs)
typedef __attribute__((ext_vector_type(4))) float f32x4;

static __device__ __forceinline__ unsigned short f2bf(float f) {
    unsigned int u = __float_as_uint(f);
    unsigned int r = (u + 0x7fff + ((u >> 16) & 1)) >> 16;  // round-to-nearest-even
    return (unsigned short)r;
}

// ---------------------------------------------------------------------------
// Bt[n][k] bf16, n in [0,256): cols 0..127 = W, 128..255 = W_res.
// Transposed so MFMA B-fragments are contiguous 16B runs along k.
// ---------------------------------------------------------------------------
__global__ void wconv_kernel(const float* __restrict__ W,
                             const float* __restrict__ Wr,
                             unsigned short* __restrict__ Bt)
{
    int k = threadIdx.x;          // 0..127
    int n = blockIdx.x;           // 0..255
    float v = (n < 128) ? W[(size_t)k * 128 + n] : Wr[(size_t)k * 128 + (n - 128)];
    Bt[n * 128 + k] = f2bf(v);
}

// ---------------------------------------------------------------------------
// proj_mfma: x = feat@W -> ws, res = feat@W_res -> d_out, bf16 MFMA.
// Block = 256 thr (4 waves), 64 nodes/block. Wave w computes 16 nodes x 256
// cols via 16 N-tiles of 16x16x32 MFMA (4 k-chunks each, K=128).
// A staged in LDS bf16 [64][136] (pad 8 -> <=2-way banks, 16B aligned reads).
// B-frags read straight from global (L2/L1-resident 64KB).
// ---------------------------------------------------------------------------
__global__ __launch_bounds__(256)
void proj_mfma(const float* __restrict__ feat,
               const unsigned short* __restrict__ Bt,
               float* __restrict__ x,
               float* __restrict__ out)
{
    __shared__ unsigned short As[64 * 136];
    const int tid  = threadIdx.x;
    const int base = blockIdx.x * 64;

    // stage A: 64 rows x 128 cols fp32 -> bf16 LDS, coalesced float4 loads
    #pragma unroll
    for (int it = 0; it < 8; ++it) {
        int idx = it * 256 + tid;       // over [64][32] float4 grid
        int row = idx >> 5;
        int c4  = idx & 31;
        int n = base + row;
        if (n < NN) {
            const float4 f = *(const float4*)&feat[(size_t)n * F_IN + c4 * 4];
            ushort4 h;
            h.x = f2bf(f.x); h.y = f2bf(f.y); h.z = f2bf(f.z); h.w = f2bf(f.w);
            *(ushort4*)&As[row * 136 + c4 * 4] = h;
        }
    }
    __syncthreads();

    const int l = tid & 63;
    const int w = tid >> 6;
    const int quad = l >> 4;
    const int lo16 = l & 15;

    // A fragments: row = w*16 + lo16, k = quad*8 + kc*32 (+j)
    short8 af[4];
    const int arow = w * 16 + lo16;
    #pragma unroll
    for (int kc = 0; kc < 4; ++kc)
        af[kc] = *(const short8*)&As[arow * 136 + kc * 32 + quad * 8];

    f32x4 acc[16];
    #pragma unroll
    for (int nt = 0; nt < 16; ++nt) acc[nt] = (f32x4){0.f, 0.f, 0.f, 0.f};

    #pragma unroll 2
    for (int nt = 0; nt < 16; ++nt) {
        const unsigned short* bp = &Bt[(size_t)(nt * 16 + lo16) * 128 + quad * 8];
        short8 b0 = *(const short8*)&bp[0];
        short8 b1 = *(const short8*)&bp[32];
        short8 b2 = *(const short8*)&bp[64];
        short8 b3 = *(const short8*)&bp[96];
        acc[nt] = __builtin_amdgcn_mfma_f32_16x16x32_bf16(af[0], b0, acc[nt], 0, 0, 0);
        acc[nt] = __builtin_amdgcn_mfma_f32_16x16x32_bf16(af[1], b1, acc[nt], 0, 0, 0);
        acc[nt] = __builtin_amdgcn_mfma_f32_16x16x32_bf16(af[2], b2, acc[nt], 0, 0, 0);
        acc[nt] = __builtin_amdgcn_mfma_f32_16x16x32_bf16(af[3], b3, acc[nt], 0, 0, 0);
    }

    // epilogue: C/D layout col = lane&15, row = (lane>>4)*4 + reg
    const int rbase = base + w * 16 + quad * 4;
    #pragma unroll
    for (int nt = 0; nt < 16; ++nt) {
        const int c = nt * 16 + lo16;
        #pragma unroll
        for (int r = 0; r < 4; ++r) {
            int node = rbase + r;
            if (node < NN) {
                if (nt < 8) x  [(size_t)node * C + c]         = acc[nt][r];
                else        out[(size_t)node * C + (c - 128)] = acc[nt][r];
            }
        }
    }
}

// ---------------------------------------------------------------------------
// attention logits from x (fp32): a_s[n,h] = sum_f x[n,h,f]*att_src[h,f]
// ---------------------------------------------------------------------------
__global__ __launch_bounds__(256)
void logits_kernel(const float* __restrict__ x,
                   const float* __restrict__ att_src,
                   const float* __restrict__ att_dst,
                   float* __restrict__ a_s,
                   float* __restrict__ a_d)
{
    const int t = threadIdx.x & 127;
    const int n = blockIdx.x * 2 + (threadIdx.x >> 7);
    if (n >= NN) return;
    const int h = t >> 5;
    float v  = x[(size_t)n * C + t];
    float ps = v * att_src[t];
    float pd = v * att_dst[t];
    #pragma unroll
    for (int d = 16; d > 0; d >>= 1) {
        ps += __shfl_down(ps, d, 32);
        pd += __shfl_down(pd, d, 32);
    }
    if ((t & 31) == 0) { a_s[n * 4 + h] = ps; a_d[n * 4 + h] = pd; }
}

// ---------------------------------------------------------------------------
__global__ void hist_kernel(const int* __restrict__ dst, int* __restrict__ deg)
{
    int e = blockIdx.x * blockDim.x + threadIdx.x;
    if (e < NE) atomicAdd(&deg[dst[e]], 1);
}

// ---------------------------------------------------------------------------
// multi-block exclusive scan: scan1 (per-block) -> scan2 (block sums) -> scan3
// ---------------------------------------------------------------------------
__global__ __launch_bounds__(1024)
void scan1_kernel(const int* __restrict__ deg, int* __restrict__ row_ptr,
                  int* __restrict__ bsum)
{
    __shared__ int wsum[16];
    const int t = threadIdx.x, lane = t & 63, wid = t >> 6;
    const int i = blockIdx.x * 1024 + t;
    int v0 = (i < NN) ? deg[i] : 0;
    int v = v0;
    #pragma unroll
    for (int off = 1; off < 64; off <<= 1) {
        int u = __shfl_up(v, off, 64);
        if (lane >= off) v += u;
    }
    if (lane == 63) wsum[wid] = v;
    __syncthreads();
    if (t == 0) {
        int run = 0;
        #pragma unroll
        for (int s = 0; s < 16; ++s) { int tmp = wsum[s]; wsum[s] = run; run += tmp; }
        bsum[blockIdx.x] = run;
    }
    __syncthreads();
    if (i < NN) row_ptr[i] = wsum[wid] + (v - v0);
}

__global__ __launch_bounds__(128)
void scan2_kernel(int* __restrict__ bsum)   // SCAN_NB <= 128
{
    __shared__ int w0;
    const int t = threadIdx.x, lane = t & 63;
    int v0 = (t < SCAN_NB) ? bsum[t] : 0;
    int v = v0;
    #pragma unroll
    for (int off = 1; off < 64; off <<= 1) {
        int u = __shfl_up(v, off, 64);
        if (lane >= off) v += u;
    }
    if (t == 63) w0 = v;
    __syncthreads();
    int excl = (v - v0) + ((t >= 64) ? w0 : 0);
    if (t < SCAN_NB) bsum[t] = excl;
}

__global__ __launch_bounds__(1024)
void scan3_kernel(int* __restrict__ row_ptr, const int* __restrict__ bsum,
                  int* __restrict__ cursor)
{
    const int i = blockIdx.x * 1024 + threadIdx.x;
    if (i < NN) {
        int r = row_ptr[i] + bsum[i >> 10];
        row_ptr[i] = r;
        cursor[i] = r;
    }
    if (i == 0) row_ptr[NN] = NE;
}

// ---------------------------------------------------------------------------
__global__ void scatter_kernel(const int* __restrict__ src,
                               const int* __restrict__ dst,
                               int* __restrict__ cursor,
                               int* __restrict__ csr_src)
{
    int e = blockIdx.x * blockDim.x + threadIdx.x;
    if (e < NE) {
        int d = dst[e];
        int pos = atomicAdd(&cursor[d], 1);
        csr_src[pos] = src[e];
    }
}

// ---------------------------------------------------------------------------
// aggregation: one 128-thread block per dst node (unchanged from round 1)
// ---------------------------------------------------------------------------
__global__ __launch_bounds__(128)
void agg_kernel(const float* __restrict__ x,
                const float* __restrict__ a_s,
                const float* __restrict__ a_d,
                const int* __restrict__ row_ptr,
                const int* __restrict__ csr_src,
                float* __restrict__ out)
{
    __shared__ int   s_src[32];
    __shared__ float s_alpha[32 * 4];
    const int n = blockIdx.x;
    const int t = threadIdx.x;
    const int h = t >> 5;
    const int l = t & 31;
    const int r0  = row_ptr[n];
    const int deg = row_ptr[n + 1] - r0;
    if (deg == 0) return;

    const float adn = a_d[n * 4 + h];

    float m = -1e30f;
    for (int i = l; i < deg; i += 32) {
        int s = csr_src[r0 + i];
        float e = a_s[s * 4 + h] + adn;
        e = (e > 0.f) ? e : NEG_SLOPE * e;
        m = fmaxf(m, e);
    }
    #pragma unroll
    for (int d = 16; d > 0; d >>= 1) m = fmaxf(m, __shfl_down(m, d, 32));
    m = __shfl(m, 0, 32);

    float ssum = 0.f;
    for (int i = l; i < deg; i += 32) {
        int s = csr_src[r0 + i];
        float e = a_s[s * 4 + h] + adn;
        e = (e > 0.f) ? e : NEG_SLOPE * e;
        ssum += __expf(e - m);
    }
    #pragma unroll
    for (int d = 16; d > 0; d >>= 1) ssum += __shfl_down(ssum, d, 32);
    ssum = __shfl(ssum, 0, 32);
    const float inv = 1.f / ssum;

    float acc = 0.f;
    for (int c0 = 0; c0 < deg; c0 += 32) {
        int cn = min(32, deg - c0);
        __syncthreads();
        if (t < cn) s_src[t] = csr_src[r0 + c0 + t];
        __syncthreads();
        if (l < cn) {
            int s = s_src[l];
            float e = a_s[s * 4 + h] + adn;
            e = (e > 0.f) ? e : NEG_SLOPE * e;
            s_alpha[l * 4 + h] = __expf(e - m) * inv;
        }
        __syncthreads();
        for (int i = 0; i < cn; ++i) {
            acc = fmaf(s_alpha[i * 4 + h], x[(size_t)s_src[i] * C + t], acc);
        }
    }
    out[(size_t)n * C + t] += acc;
}

// ---------------------------------------------------------------------------
extern "C" void kernel_launch(void* const* d_in, const int* in_sizes, int n_in,
                              void* d_out, int out_size, void* d_ws, size_t ws_size,
                              hipStream_t stream)
{
    const float* feat    = (const float*)d_in[0];
    const float* W       = (const float*)d_in[1];
    const float* att_src = (const float*)d_in[2];
    const float* att_dst = (const float*)d_in[3];
    const float* W_res   = (const float*)d_in[4];
    const int*   src     = (const int*)d_in[5];
    const int*   dst     = (const int*)d_in[6];
    float* out = (float*)d_out;

    char* p = (char*)d_ws;
    float* x   = (float*)p;            p += (size_t)NN * C * sizeof(float);   // 51.2 MB
    unsigned short* Bt = (unsigned short*)p; p += (size_t)256 * 128 * sizeof(unsigned short);
    float* a_s = (float*)p;            p += (size_t)NN * 4 * sizeof(float);
    float* a_d = (float*)p;            p += (size_t)NN * 4 * sizeof(float);
    int* deg     = (int*)p;            p += (size_t)NN * sizeof(int);
    int* row_ptr = (int*)p;            p += (size_t)(NN + 1) * sizeof(int);
    int* cursor  = (int*)p;            p += (size_t)NN * sizeof(int);
    int* bsum    = (int*)p;            p += (size_t)256 * sizeof(int);
    int* csr_src = (int*)p;            p += (size_t)NE * sizeof(int);

    hipMemsetAsync(deg, 0, (size_t)NN * sizeof(int), stream);

    wconv_kernel<<<256, 128, 0, stream>>>(W, W_res, Bt);
    proj_mfma<<<(NN + 63) / 64, 256, 0, stream>>>(feat, Bt, x, out);
    logits_kernel<<<(NN + 1) / 2, 256, 0, stream>>>(x, att_src, att_dst, a_s, a_d);
    hist_kernel<<<(NE + 255) / 256, 256, 0, stream>>>(dst, deg);
    scan1_kernel<<<SCAN_NB, 1024, 0, stream>>>(deg, row_ptr, bsum);
    scan2_kernel<<<1, 128, 0, stream>>>(bsum);
    scan3_kernel<<<SCAN_NB, 1024, 0, stream>>>(row_ptr, bsum, cursor);
    scatter_kernel<<<(NE + 255) / 256, 256, 0, stream>>>(src, dst, cursor, csr_src);
    agg_kernel<<<NN, 128, 0, stream>>>(x, a_s, a_d, row_ptr, csr_src, out);
}

// Round 3
// 557.812 us; speedup vs baseline: 1.2955x; 1.1318x over previous
//
#include <hip/hip_runtime.h>
#include <math.h>

#define NN 100000
#define NE 1600000
#define F_IN 128
#define C 128           // N_HEADS * F_OUT
#define NEG_SLOPE 0.2f
#define SCAN_NB ((NN + 1023) / 1024)   // 98

typedef __attribute__((ext_vector_type(8))) short short8;   // 8 x bf16 (4 VGPRs)
typedef __attribute__((ext_vector_type(4))) float f32x4;

static __device__ __forceinline__ unsigned short f2bf(float f) {
    unsigned int u = __float_as_uint(f);
    unsigned int r = (u + 0x7fff + ((u >> 16) & 1)) >> 16;  // RNE
    return (unsigned short)r;
}
static __device__ __forceinline__ float bf2f(unsigned short h) {
    return __uint_as_float((unsigned int)h << 16);
}

// ---------------------------------------------------------------------------
// Bt[n][k] bf16, n in [0,256): cols 0..127 = W, 128..255 = W_res.
// ---------------------------------------------------------------------------
__global__ void wconv_kernel(const float* __restrict__ W,
                             const float* __restrict__ Wr,
                             unsigned short* __restrict__ Bt)
{
    int k = threadIdx.x;          // 0..127
    int n = blockIdx.x;           // 0..255
    float v = (n < 128) ? W[(size_t)k * 128 + n] : Wr[(size_t)k * 128 + (n - 128)];
    Bt[n * 128 + k] = f2bf(v);
}

// ---------------------------------------------------------------------------
// proj_mfma: x(bf16) = feat@W -> ws, res(fp32) = feat@W_res -> d_out.
// Fused logits: a_s[n,h], a_d[n,h] from fp32 accumulators.
// Epilogue transposes acc through per-wave LDS so global stores are full
// contiguous rows (256B/512B segments) -- fixes round-2's 3.15x write
// amplification from 64B scattered segments.
// LDS: A-stage (17.4KB) overlaid by 4x transpose buffers (33.8KB max).
// ---------------------------------------------------------------------------
__global__ __launch_bounds__(256)
void proj_mfma(const float* __restrict__ feat,
               const unsigned short* __restrict__ Bt,
               const float* __restrict__ att_src,
               const float* __restrict__ att_dst,
               unsigned short* __restrict__ xb,
               float* __restrict__ a_s,
               float* __restrict__ a_d,
               float* __restrict__ out)
{
    __shared__ __align__(16) char smem[4 * 16 * 132 * 4];   // 33792 B
    unsigned short* As = (unsigned short*)smem;             // [64][136] bf16
    const int tid  = threadIdx.x;
    const int base = blockIdx.x * 64;

    // stage A: 64 rows x 128 cols fp32 -> bf16 LDS
    #pragma unroll
    for (int it = 0; it < 8; ++it) {
        int idx = it * 256 + tid;       // over [64][32] float4 grid
        int row = idx >> 5;
        int c4  = idx & 31;
        int n = base + row;
        if (n < NN) {
            const float4 f = *(const float4*)&feat[(size_t)n * F_IN + c4 * 4];
            ushort4 h;
            h.x = f2bf(f.x); h.y = f2bf(f.y); h.z = f2bf(f.z); h.w = f2bf(f.w);
            *(ushort4*)&As[row * 136 + c4 * 4] = h;
        }
    }
    __syncthreads();

    const int l = tid & 63;
    const int w = tid >> 6;
    const int quad = l >> 4;
    const int lo16 = l & 15;

    // A fragments: row = w*16 + lo16, k = kc*32 + quad*8 + j
    short8 af[4];
    const int arow = w * 16 + lo16;
    #pragma unroll
    for (int kc = 0; kc < 4; ++kc)
        af[kc] = *(const short8*)&As[arow * 136 + kc * 32 + quad * 8];
    __syncthreads();    // As dead; LDS reused as transpose buffers

    f32x4 acc[16];
    #pragma unroll
    for (int nt = 0; nt < 16; ++nt) acc[nt] = (f32x4){0.f, 0.f, 0.f, 0.f};

    #pragma unroll 2
    for (int nt = 0; nt < 16; ++nt) {
        const unsigned short* bp = &Bt[(size_t)(nt * 16 + lo16) * 128 + quad * 8];
        short8 b0 = *(const short8*)&bp[0];
        short8 b1 = *(const short8*)&bp[32];
        short8 b2 = *(const short8*)&bp[64];
        short8 b3 = *(const short8*)&bp[96];
        acc[nt] = __builtin_amdgcn_mfma_f32_16x16x32_bf16(af[0], b0, acc[nt], 0, 0, 0);
        acc[nt] = __builtin_amdgcn_mfma_f32_16x16x32_bf16(af[1], b1, acc[nt], 0, 0, 0);
        acc[nt] = __builtin_amdgcn_mfma_f32_16x16x32_bf16(af[2], b2, acc[nt], 0, 0, 0);
        acc[nt] = __builtin_amdgcn_mfma_f32_16x16x32_bf16(af[3], b3, acc[nt], 0, 0, 0);
    }

    // per-wave transpose buffer: T[16][132] floats (wave-private => no barrier)
    float* T = (float*)smem + w * 16 * 132;

    // ---- pass 0: x columns (nt 0..7) + fused logits ----
    #pragma unroll
    for (int nt = 0; nt < 8; ++nt) {
        #pragma unroll
        for (int r = 0; r < 4; ++r)
            T[(quad * 4 + r) * 132 + nt * 16 + lo16] = acc[nt][r];
    }
    #pragma unroll
    for (int i = 0; i < 8; ++i) {
        int flat = i * 256 + l * 4;     // 0..2047
        int row  = flat >> 7;           // 2i or 2i+1
        int col  = flat & 127;
        float4 v = *(float4*)&T[row * 132 + col];
        int node = base + w * 16 + row;
        // bf16 store: 64 lanes x 8B = two 256B row segments
        if (node < NN) {
            ushort4 h;
            h.x = f2bf(v.x); h.y = f2bf(v.y); h.z = f2bf(v.z); h.w = f2bf(v.w);
            *(ushort4*)&xb[(size_t)node * C + col] = h;
        }
        // fused logits: head = col>>5, 8-lane groups per (row, head)
        float4 ws = *(const float4*)&att_src[col];
        float4 wd = *(const float4*)&att_dst[col];
        float ps = v.x * ws.x + v.y * ws.y + v.z * ws.z + v.w * ws.w;
        float pd = v.x * wd.x + v.y * wd.y + v.z * wd.z + v.w * wd.w;
        #pragma unroll
        for (int d = 4; d > 0; d >>= 1) {
            ps += __shfl_down(ps, d, 64);
            pd += __shfl_down(pd, d, 64);
        }
        if ((l & 7) == 0 && node < NN) {
            int h = (l & 31) >> 3;
            a_s[node * 4 + h] = ps;
            a_d[node * 4 + h] = pd;
        }
    }

    // ---- pass 1: out columns (nt 8..15), fp32 ----
    #pragma unroll
    for (int nt = 8; nt < 16; ++nt) {
        #pragma unroll
        for (int r = 0; r < 4; ++r)
            T[(quad * 4 + r) * 132 + (nt - 8) * 16 + lo16] = acc[nt][r];
    }
    #pragma unroll
    for (int i = 0; i < 8; ++i) {
        int flat = i * 256 + l * 4;
        int row  = flat >> 7;
        int col  = flat & 127;
        float4 v = *(float4*)&T[row * 132 + col];
        int node = base + w * 16 + row;
        if (node < NN)
            *(float4*)&out[(size_t)node * C + col] = v;   // 2 x 512B segments
    }
}

// ---------------------------------------------------------------------------
__global__ void hist_kernel(const int* __restrict__ dst, int* __restrict__ deg)
{
    int e = blockIdx.x * blockDim.x + threadIdx.x;
    if (e < NE) atomicAdd(&deg[dst[e]], 1);
}

// ---------------------------------------------------------------------------
// multi-block exclusive scan
// ---------------------------------------------------------------------------
__global__ __launch_bounds__(1024)
void scan1_kernel(const int* __restrict__ deg, int* __restrict__ row_ptr,
                  int* __restrict__ bsum)
{
    __shared__ int wsum[16];
    const int t = threadIdx.x, lane = t & 63, wid = t >> 6;
    const int i = blockIdx.x * 1024 + t;
    int v0 = (i < NN) ? deg[i] : 0;
    int v = v0;
    #pragma unroll
    for (int off = 1; off < 64; off <<= 1) {
        int u = __shfl_up(v, off, 64);
        if (lane >= off) v += u;
    }
    if (lane == 63) wsum[wid] = v;
    __syncthreads();
    if (t == 0) {
        int run = 0;
        #pragma unroll
        for (int s = 0; s < 16; ++s) { int tmp = wsum[s]; wsum[s] = run; run += tmp; }
        bsum[blockIdx.x] = run;
    }
    __syncthreads();
    if (i < NN) row_ptr[i] = wsum[wid] + (v - v0);
}

__global__ __launch_bounds__(128)
void scan2_kernel(int* __restrict__ bsum)
{
    __shared__ int w0;
    const int t = threadIdx.x, lane = t & 63;
    int v0 = (t < SCAN_NB) ? bsum[t] : 0;
    int v = v0;
    #pragma unroll
    for (int off = 1; off < 64; off <<= 1) {
        int u = __shfl_up(v, off, 64);
        if (lane >= off) v += u;
    }
    if (t == 63) w0 = v;
    __syncthreads();
    int excl = (v - v0) + ((t >= 64) ? w0 : 0);
    if (t < SCAN_NB) bsum[t] = excl;
}

__global__ __launch_bounds__(1024)
void scan3_kernel(int* __restrict__ row_ptr, const int* __restrict__ bsum,
                  int* __restrict__ cursor)
{
    const int i = blockIdx.x * 1024 + threadIdx.x;
    if (i < NN) {
        int r = row_ptr[i] + bsum[i >> 10];
        row_ptr[i] = r;
        cursor[i] = r;
    }
    if (i == 0) row_ptr[NN] = NE;
}

// ---------------------------------------------------------------------------
__global__ void scatter_kernel(const int* __restrict__ src,
                               const int* __restrict__ dst,
                               int* __restrict__ cursor,
                               int* __restrict__ csr_src)
{
    int e = blockIdx.x * blockDim.x + threadIdx.x;
    if (e < NE) {
        int d = dst[e];
        int pos = atomicAdd(&cursor[d], 1);
        csr_src[pos] = src[e];
    }
}

// ---------------------------------------------------------------------------
// aggregation: one 128-thread block per dst node; x gather is bf16 (256B/row)
// ---------------------------------------------------------------------------
__global__ __launch_bounds__(128)
void agg_kernel(const unsigned short* __restrict__ xb,
                const float* __restrict__ a_s,
                const float* __restrict__ a_d,
                const int* __restrict__ row_ptr,
                const int* __restrict__ csr_src,
                float* __restrict__ out)
{
    __shared__ int   s_src[32];
    __shared__ float s_alpha[32 * 4];
    const int n = blockIdx.x;
    const int t = threadIdx.x;
    const int h = t >> 5;
    const int l = t & 31;
    const int r0  = row_ptr[n];
    const int deg = row_ptr[n + 1] - r0;
    if (deg == 0) return;

    const float adn = a_d[n * 4 + h];

    float m = -1e30f;
    for (int i = l; i < deg; i += 32) {
        int s = csr_src[r0 + i];
        float e = a_s[s * 4 + h] + adn;
        e = (e > 0.f) ? e : NEG_SLOPE * e;
        m = fmaxf(m, e);
    }
    #pragma unroll
    for (int d = 16; d > 0; d >>= 1) m = fmaxf(m, __shfl_down(m, d, 32));
    m = __shfl(m, 0, 32);

    float ssum = 0.f;
    for (int i = l; i < deg; i += 32) {
        int s = csr_src[r0 + i];
        float e = a_s[s * 4 + h] + adn;
        e = (e > 0.f) ? e : NEG_SLOPE * e;
        ssum += __expf(e - m);
    }
    #pragma unroll
    for (int d = 16; d > 0; d >>= 1) ssum += __shfl_down(ssum, d, 32);
    ssum = __shfl(ssum, 0, 32);
    const float inv = 1.f / ssum;

    float acc = 0.f;
    for (int c0 = 0; c0 < deg; c0 += 32) {
        int cn = min(32, deg - c0);
        __syncthreads();
        if (t < cn) s_src[t] = csr_src[r0 + c0 + t];
        __syncthreads();
        if (l < cn) {
            int s = s_src[l];
            float e = a_s[s * 4 + h] + adn;
            e = (e > 0.f) ? e : NEG_SLOPE * e;
            s_alpha[l * 4 + h] = __expf(e - m) * inv;
        }
        __syncthreads();
        for (int i = 0; i < cn; ++i) {
            acc = fmaf(s_alpha[i * 4 + h],
                       bf2f(xb[(size_t)s_src[i] * C + t]), acc);
        }
    }
    out[(size_t)n * C + t] += acc;
}

// ---------------------------------------------------------------------------
extern "C" void kernel_launch(void* const* d_in, const int* in_sizes, int n_in,
                              void* d_out, int out_size, void* d_ws, size_t ws_size,
                              hipStream_t stream)
{
    const float* feat    = (const float*)d_in[0];
    const float* W       = (const float*)d_in[1];
    const float* att_src = (const float*)d_in[2];
    const float* att_dst = (const float*)d_in[3];
    const float* W_res   = (const float*)d_in[4];
    const int*   src     = (const int*)d_in[5];
    const int*   dst     = (const int*)d_in[6];
    float* out = (float*)d_out;

    char* p = (char*)d_ws;
    unsigned short* xb = (unsigned short*)p; p += (size_t)NN * C * sizeof(unsigned short); // 25.6 MB
    unsigned short* Bt = (unsigned short*)p; p += (size_t)256 * 128 * sizeof(unsigned short);
    float* a_s = (float*)p;            p += (size_t)NN * 4 * sizeof(float);
    float* a_d = (float*)p;            p += (size_t)NN * 4 * sizeof(float);
    int* deg     = (int*)p;            p += (size_t)NN * sizeof(int);
    int* row_ptr = (int*)p;            p += (size_t)(NN + 1) * sizeof(int);
    int* cursor  = (int*)p;            p += (size_t)NN * sizeof(int);
    int* bsum    = (int*)p;            p += (size_t)256 * sizeof(int);
    int* csr_src = (int*)p;            p += (size_t)NE * sizeof(int);

    hipMemsetAsync(deg, 0, (size_t)NN * sizeof(int), stream);

    wconv_kernel<<<256, 128, 0, stream>>>(W, W_res, Bt);
    proj_mfma<<<(NN + 63) / 64, 256, 0, stream>>>(feat, Bt, att_src, att_dst,
                                                  xb, a_s, a_d, out);
    hist_kernel<<<(NE + 255) / 256, 256, 0, stream>>>(dst, deg);
    scan1_kernel<<<SCAN_NB, 1024, 0, stream>>>(deg, row_ptr, bsum);
    scan2_kernel<<<1, 128, 0, stream>>>(bsum);
    scan3_kernel<<<SCAN_NB, 1024, 0, stream>>>(row_ptr, bsum, cursor);
    scatter_kernel<<<(NE + 255) / 256, 256, 0, stream>>>(src, dst, cursor, csr_src);
    agg_kernel<<<NN, 128, 0, stream>>>(xb, a_s, a_d, row_ptr, csr_src, out);
}

// Round 4
// 419.662 us; speedup vs baseline: 1.7220x; 1.3292x over previous
//
#include <hip/hip_runtime.h>
#include <math.h>

#define NN 100000
#define NE 1600000
#define F_IN 128
#define C 128           // N_HEADS * F_OUT
#define NEG_SLOPE 0.2f
#define SCAN_NB ((NN + 1023) / 1024)   // 98

typedef __attribute__((ext_vector_type(8))) short short8;   // 8 x bf16 (4 VGPRs)
typedef __attribute__((ext_vector_type(4))) float f32x4;

static __device__ __forceinline__ unsigned short f2bf(float f) {
    unsigned int u = __float_as_uint(f);
    unsigned int r = (u + 0x7fff + ((u >> 16) & 1)) >> 16;  // RNE
    return (unsigned short)r;
}
static __device__ __forceinline__ float bf2f(unsigned short h) {
    return __uint_as_float((unsigned int)h << 16);
}

// ---------------------------------------------------------------------------
// Bt[n][k] bf16, n in [0,256): cols 0..127 = W, 128..255 = W_res.
// ---------------------------------------------------------------------------
__global__ void wconv_kernel(const float* __restrict__ W,
                             const float* __restrict__ Wr,
                             unsigned short* __restrict__ Bt)
{
    int k = threadIdx.x;          // 0..127
    int n = blockIdx.x;           // 0..255
    float v = (n < 128) ? W[(size_t)k * 128 + n] : Wr[(size_t)k * 128 + (n - 128)];
    Bt[n * 128 + k] = f2bf(v);
}

// ---------------------------------------------------------------------------
// proj_mfma (unchanged from round 3): x(bf16), res(fp32)->out, fused logits.
// ---------------------------------------------------------------------------
__global__ __launch_bounds__(256)
void proj_mfma(const float* __restrict__ feat,
               const unsigned short* __restrict__ Bt,
               const float* __restrict__ att_src,
               const float* __restrict__ att_dst,
               unsigned short* __restrict__ xb,
               float* __restrict__ a_s,
               float* __restrict__ a_d,
               float* __restrict__ out)
{
    __shared__ __align__(16) char smem[4 * 16 * 132 * 4];   // 33792 B
    unsigned short* As = (unsigned short*)smem;             // [64][136] bf16
    const int tid  = threadIdx.x;
    const int base = blockIdx.x * 64;

    #pragma unroll
    for (int it = 0; it < 8; ++it) {
        int idx = it * 256 + tid;
        int row = idx >> 5;
        int c4  = idx & 31;
        int n = base + row;
        if (n < NN) {
            const float4 f = *(const float4*)&feat[(size_t)n * F_IN + c4 * 4];
            ushort4 h;
            h.x = f2bf(f.x); h.y = f2bf(f.y); h.z = f2bf(f.z); h.w = f2bf(f.w);
            *(ushort4*)&As[row * 136 + c4 * 4] = h;
        }
    }
    __syncthreads();

    const int l = tid & 63;
    const int w = tid >> 6;
    const int quad = l >> 4;
    const int lo16 = l & 15;

    short8 af[4];
    const int arow = w * 16 + lo16;
    #pragma unroll
    for (int kc = 0; kc < 4; ++kc)
        af[kc] = *(const short8*)&As[arow * 136 + kc * 32 + quad * 8];
    __syncthreads();

    f32x4 acc[16];
    #pragma unroll
    for (int nt = 0; nt < 16; ++nt) acc[nt] = (f32x4){0.f, 0.f, 0.f, 0.f};

    #pragma unroll 2
    for (int nt = 0; nt < 16; ++nt) {
        const unsigned short* bp = &Bt[(size_t)(nt * 16 + lo16) * 128 + quad * 8];
        short8 b0 = *(const short8*)&bp[0];
        short8 b1 = *(const short8*)&bp[32];
        short8 b2 = *(const short8*)&bp[64];
        short8 b3 = *(const short8*)&bp[96];
        acc[nt] = __builtin_amdgcn_mfma_f32_16x16x32_bf16(af[0], b0, acc[nt], 0, 0, 0);
        acc[nt] = __builtin_amdgcn_mfma_f32_16x16x32_bf16(af[1], b1, acc[nt], 0, 0, 0);
        acc[nt] = __builtin_amdgcn_mfma_f32_16x16x32_bf16(af[2], b2, acc[nt], 0, 0, 0);
        acc[nt] = __builtin_amdgcn_mfma_f32_16x16x32_bf16(af[3], b3, acc[nt], 0, 0, 0);
    }

    float* T = (float*)smem + w * 16 * 132;

    // pass 0: x columns + fused logits
    #pragma unroll
    for (int nt = 0; nt < 8; ++nt) {
        #pragma unroll
        for (int r = 0; r < 4; ++r)
            T[(quad * 4 + r) * 132 + nt * 16 + lo16] = acc[nt][r];
    }
    #pragma unroll
    for (int i = 0; i < 8; ++i) {
        int flat = i * 256 + l * 4;
        int row  = flat >> 7;
        int col  = flat & 127;
        float4 v = *(float4*)&T[row * 132 + col];
        int node = base + w * 16 + row;
        if (node < NN) {
            ushort4 h;
            h.x = f2bf(v.x); h.y = f2bf(v.y); h.z = f2bf(v.z); h.w = f2bf(v.w);
            *(ushort4*)&xb[(size_t)node * C + col] = h;
        }
        float4 ws = *(const float4*)&att_src[col];
        float4 wd = *(const float4*)&att_dst[col];
        float ps = v.x * ws.x + v.y * ws.y + v.z * ws.z + v.w * ws.w;
        float pd = v.x * wd.x + v.y * wd.y + v.z * wd.z + v.w * wd.w;
        #pragma unroll
        for (int d = 4; d > 0; d >>= 1) {
            ps += __shfl_down(ps, d, 64);
            pd += __shfl_down(pd, d, 64);
        }
        if ((l & 7) == 0 && node < NN) {
            int h = (l & 31) >> 3;
            a_s[node * 4 + h] = ps;
            a_d[node * 4 + h] = pd;
        }
    }

    // pass 1: out columns fp32
    #pragma unroll
    for (int nt = 8; nt < 16; ++nt) {
        #pragma unroll
        for (int r = 0; r < 4; ++r)
            T[(quad * 4 + r) * 132 + (nt - 8) * 16 + lo16] = acc[nt][r];
    }
    #pragma unroll
    for (int i = 0; i < 8; ++i) {
        int flat = i * 256 + l * 4;
        int row  = flat >> 7;
        int col  = flat & 127;
        float4 v = *(float4*)&T[row * 132 + col];
        int node = base + w * 16 + row;
        if (node < NN)
            *(float4*)&out[(size_t)node * C + col] = v;
    }
}

// ---------------------------------------------------------------------------
// hist: degree histogram; also records each edge's rank within its dst bucket
// (atomicAdd return value), so scatter needs NO atomics.
// ---------------------------------------------------------------------------
__global__ void hist_kernel(const int* __restrict__ dst, int* __restrict__ deg,
                            int* __restrict__ rank)
{
    int e = blockIdx.x * blockDim.x + threadIdx.x;
    if (e < NE) rank[e] = atomicAdd(&deg[dst[e]], 1);
}

// ---------------------------------------------------------------------------
// multi-block exclusive scan
// ---------------------------------------------------------------------------
__global__ __launch_bounds__(1024)
void scan1_kernel(const int* __restrict__ deg, int* __restrict__ row_ptr,
                  int* __restrict__ bsum)
{
    __shared__ int wsum[16];
    const int t = threadIdx.x, lane = t & 63, wid = t >> 6;
    const int i = blockIdx.x * 1024 + t;
    int v0 = (i < NN) ? deg[i] : 0;
    int v = v0;
    #pragma unroll
    for (int off = 1; off < 64; off <<= 1) {
        int u = __shfl_up(v, off, 64);
        if (lane >= off) v += u;
    }
    if (lane == 63) wsum[wid] = v;
    __syncthreads();
    if (t == 0) {
        int run = 0;
        #pragma unroll
        for (int s = 0; s < 16; ++s) { int tmp = wsum[s]; wsum[s] = run; run += tmp; }
        bsum[blockIdx.x] = run;
    }
    __syncthreads();
    if (i < NN) row_ptr[i] = wsum[wid] + (v - v0);
}

__global__ __launch_bounds__(128)
void scan2_kernel(int* __restrict__ bsum)
{
    __shared__ int w0;
    const int t = threadIdx.x, lane = t & 63;
    int v0 = (t < SCAN_NB) ? bsum[t] : 0;
    int v = v0;
    #pragma unroll
    for (int off = 1; off < 64; off <<= 1) {
        int u = __shfl_up(v, off, 64);
        if (lane >= off) v += u;
    }
    if (t == 63) w0 = v;
    __syncthreads();
    int excl = (v - v0) + ((t >= 64) ? w0 : 0);
    if (t < SCAN_NB) bsum[t] = excl;
}

__global__ __launch_bounds__(1024)
void scan3_kernel(int* __restrict__ row_ptr, const int* __restrict__ bsum)
{
    const int i = blockIdx.x * 1024 + threadIdx.x;
    if (i < NN) row_ptr[i] = row_ptr[i] + bsum[i >> 10];
    if (i == 0) row_ptr[NN] = NE;
}

// ---------------------------------------------------------------------------
// scatter: pure load->store, no atomics (rank precomputed in hist)
// ---------------------------------------------------------------------------
__global__ void scatter_kernel(const int* __restrict__ src,
                               const int* __restrict__ dst,
                               const int* __restrict__ rank,
                               const int* __restrict__ row_ptr,
                               int* __restrict__ csr_src)
{
    int e = blockIdx.x * blockDim.x + threadIdx.x;
    if (e < NE)
        csr_src[row_ptr[dst[e]] + rank[e]] = src[e];
}

// ---------------------------------------------------------------------------
// aggregation: one WAVE per dst node (4 nodes / 256-thr block), single pass.
// No max-subtraction (|logit| < ~6, exp safe in fp32; softmax shift-invariant).
// Lane l computes edge c0+l's exp(e) for all 4 heads (float4 a_s gather),
// denominators accumulate in registers. Inner loop: 2 edges/iter, half-wave
// per edge, ushort4 (8B) bf16 gather = 512B per wave instruction.
// ---------------------------------------------------------------------------
__global__ __launch_bounds__(256)
void agg_kernel(const unsigned short* __restrict__ xb,
                const float* __restrict__ a_s,
                const float* __restrict__ a_d,
                const int* __restrict__ row_ptr,
                const int* __restrict__ csr_src,
                float* __restrict__ out)
{
    __shared__ float s_alpha[4][64 * 4];
    __shared__ int   s_srcs[4][64];
    const int tid = threadIdx.x;
    const int w = tid >> 6;
    const int l = tid & 63;
    const int n = blockIdx.x * 4 + w;
    if (n >= NN) return;                       // wave-uniform
    const int r0  = row_ptr[n];
    const int deg = row_ptr[n + 1] - r0;
    if (deg == 0) return;                      // residual already in out

    const float4 ad4 = *(const float4*)&a_d[n * 4];
    const int half = l >> 5;                   // which edge of the pair
    const int hl   = l & 31;                   // channel-group lane
    const int h    = hl >> 3;                  // head of channels 4*hl..4*hl+3

    float ax = 0.f, ay = 0.f, az = 0.f, aw = 0.f;          // acc (4 ch)
    float dx = 0.f, dy = 0.f, dz = 0.f, dw = 0.f;          // denom partials

    for (int c0 = 0; c0 < deg; c0 += 64) {
        int e = c0 + l;
        int s = 0;
        float4 ex = {0.f, 0.f, 0.f, 0.f};
        if (e < deg) {
            s = csr_src[r0 + e];
            float4 as4 = *(const float4*)&a_s[s * 4];
            float e0 = as4.x + ad4.x, e1 = as4.y + ad4.y;
            float e2 = as4.z + ad4.z, e3 = as4.w + ad4.w;
            e0 = (e0 > 0.f) ? e0 : NEG_SLOPE * e0;
            e1 = (e1 > 0.f) ? e1 : NEG_SLOPE * e1;
            e2 = (e2 > 0.f) ? e2 : NEG_SLOPE * e2;
            e3 = (e3 > 0.f) ? e3 : NEG_SLOPE * e3;
            ex.x = __expf(e0); ex.y = __expf(e1);
            ex.z = __expf(e2); ex.w = __expf(e3);
            dx += ex.x; dy += ex.y; dz += ex.z; dw += ex.w;
        }
        s_srcs[w][l] = s;
        *(float4*)&s_alpha[w][l * 4] = ex;     // wave-private; DS ops in-order

        int cn = min(64, deg - c0);
        int iters = (cn + 1) >> 1;
        #pragma unroll 2
        for (int i = 0; i < iters; ++i) {
            int ii = i * 2 + half;             // ii==cn possible: alpha=0, s=0
            int   si = s_srcs[w][ii];
            float al = s_alpha[w][ii * 4 + h];
            ushort4 uv = *(const ushort4*)&xb[(size_t)si * C + hl * 4];
            ax = fmaf(al, bf2f(uv.x), ax);
            ay = fmaf(al, bf2f(uv.y), ay);
            az = fmaf(al, bf2f(uv.z), az);
            aw = fmaf(al, bf2f(uv.w), aw);
        }
    }

    // denominator: full-wave butterfly (covers all edges exactly once)
    #pragma unroll
    for (int d = 32; d > 0; d >>= 1) {
        dx += __shfl_xor(dx, d, 64);
        dy += __shfl_xor(dy, d, 64);
        dz += __shfl_xor(dz, d, 64);
        dw += __shfl_xor(dw, d, 64);
    }
    float den = (h == 0) ? dx : (h == 1) ? dy : (h == 2) ? dz : dw;
    float inv = 1.f / den;

    // combine the two half-wave edge partitions (same channels)
    ax += __shfl_xor(ax, 32, 64);
    ay += __shfl_xor(ay, 32, 64);
    az += __shfl_xor(az, 32, 64);
    aw += __shfl_xor(aw, 32, 64);

    if (half == 0) {
        float4 o = *(float4*)&out[(size_t)n * C + hl * 4];
        o.x += ax * inv; o.y += ay * inv; o.z += az * inv; o.w += aw * inv;
        *(float4*)&out[(size_t)n * C + hl * 4] = o;
    }
}

// ---------------------------------------------------------------------------
extern "C" void kernel_launch(void* const* d_in, const int* in_sizes, int n_in,
                              void* d_out, int out_size, void* d_ws, size_t ws_size,
                              hipStream_t stream)
{
    const float* feat    = (const float*)d_in[0];
    const float* W       = (const float*)d_in[1];
    const float* att_src = (const float*)d_in[2];
    const float* att_dst = (const float*)d_in[3];
    const float* W_res   = (const float*)d_in[4];
    const int*   src     = (const int*)d_in[5];
    const int*   dst     = (const int*)d_in[6];
    float* out = (float*)d_out;

    char* p = (char*)d_ws;
    unsigned short* xb = (unsigned short*)p; p += (size_t)NN * C * sizeof(unsigned short);
    unsigned short* Bt = (unsigned short*)p; p += (size_t)256 * 128 * sizeof(unsigned short);
    float* a_s = (float*)p;            p += (size_t)NN * 4 * sizeof(float);
    float* a_d = (float*)p;            p += (size_t)NN * 4 * sizeof(float);
    int* deg     = (int*)p;            p += (size_t)NN * sizeof(int);
    int* row_ptr = (int*)p;            p += (size_t)(NN + 1) * sizeof(int);
    int* bsum    = (int*)p;            p += (size_t)256 * sizeof(int);
    int* rank    = (int*)p;            p += (size_t)NE * sizeof(int);
    int* csr_src = (int*)p;            p += (size_t)NE * sizeof(int);

    hipMemsetAsync(deg, 0, (size_t)NN * sizeof(int), stream);

    wconv_kernel<<<256, 128, 0, stream>>>(W, W_res, Bt);
    proj_mfma<<<(NN + 63) / 64, 256, 0, stream>>>(feat, Bt, att_src, att_dst,
                                                  xb, a_s, a_d, out);
    hist_kernel<<<(NE + 255) / 256, 256, 0, stream>>>(dst, deg, rank);
    scan1_kernel<<<SCAN_NB, 1024, 0, stream>>>(deg, row_ptr, bsum);
    scan2_kernel<<<1, 128, 0, stream>>>(bsum);
    scan3_kernel<<<SCAN_NB, 1024, 0, stream>>>(row_ptr, bsum);
    scatter_kernel<<<(NE + 255) / 256, 256, 0, stream>>>(src, dst, rank, row_ptr, csr_src);
    agg_kernel<<<(NN + 3) / 4, 256, 0, stream>>>(xb, a_s, a_d, row_ptr, csr_src, out);
}

// Round 5
// 407.083 us; speedup vs baseline: 1.7752x; 1.0309x over previous
//
#include <hip/hip_runtime.h>
#include <math.h>

#define NN 100000
#define NE 1600000
#define F_IN 128
#define C 128           // N_HEADS * F_OUT
#define NEG_SLOPE 0.2f
#define SCAN_NB ((NN + 1023) / 1024)   // 98

typedef __attribute__((ext_vector_type(8))) short short8;   // 8 x bf16 (4 VGPRs)
typedef __attribute__((ext_vector_type(4))) float f32x4;

static __device__ __forceinline__ unsigned short f2bf(float f) {
    unsigned int u = __float_as_uint(f);
    unsigned int r = (u + 0x7fff + ((u >> 16) & 1)) >> 16;  // RNE
    return (unsigned short)r;
}
static __device__ __forceinline__ float bf2f(unsigned short h) {
    return __uint_as_float((unsigned int)h << 16);
}

// ---------------------------------------------------------------------------
// Btf: fragment-major B for mfma_f32_16x16x32_bf16.
// Btf[((nt*4+kc)*64 + lane)*8 + j] = B[k][n],  n = nt*16 + (lane&15),
//   k = kc*32 + (lane>>4)*8 + j.   n<128 -> W, else W_res.
// A wave's B-load for (nt,kc) is then base + lane*16B: 1KB contiguous.
// ---------------------------------------------------------------------------
__global__ __launch_bounds__(256)
void wconv_kernel(const float* __restrict__ W,
                  const float* __restrict__ Wr,
                  unsigned short* __restrict__ Btf)
{
    int g = blockIdx.x * 256 + threadIdx.x;   // 0..4095 = (nt,kc,lane)
    int nt = g >> 8;
    int kc = (g >> 6) & 3;
    int l  = g & 63;
    int n  = nt * 16 + (l & 15);
    int kb = kc * 32 + (l >> 4) * 8;
    unsigned short v[8];
    #pragma unroll
    for (int j = 0; j < 8; ++j) {
        int k = kb + j;
        float f = (n < 128) ? W[(size_t)k * 128 + n] : Wr[(size_t)k * 128 + (n - 128)];
        v[j] = f2bf(f);
    }
    *(short8*)&Btf[(size_t)g * 8] = *(short8*)v;
}

// ---------------------------------------------------------------------------
// proj_mfma: x(bf16) = feat@W -> ws, res(fp32) = feat@W_res -> d_out,
// fused logits. B-fragments from fragment-major Btf (coalesced 1KB loads).
// ---------------------------------------------------------------------------
__global__ __launch_bounds__(256)
void proj_mfma(const float* __restrict__ feat,
               const unsigned short* __restrict__ Btf,
               const float* __restrict__ att_src,
               const float* __restrict__ att_dst,
               unsigned short* __restrict__ xb,
               float* __restrict__ a_s,
               float* __restrict__ a_d,
               float* __restrict__ out)
{
    __shared__ __align__(16) char smem[4 * 16 * 132 * 4];   // 33792 B
    unsigned short* As = (unsigned short*)smem;             // [64][136] bf16
    const int tid  = threadIdx.x;
    const int base = blockIdx.x * 64;

    #pragma unroll
    for (int it = 0; it < 8; ++it) {
        int idx = it * 256 + tid;
        int row = idx >> 5;
        int c4  = idx & 31;
        int n = base + row;
        if (n < NN) {
            const float4 f = *(const float4*)&feat[(size_t)n * F_IN + c4 * 4];
            ushort4 h;
            h.x = f2bf(f.x); h.y = f2bf(f.y); h.z = f2bf(f.z); h.w = f2bf(f.w);
            *(ushort4*)&As[row * 136 + c4 * 4] = h;
        }
    }
    __syncthreads();

    const int l = tid & 63;
    const int w = tid >> 6;
    const int quad = l >> 4;
    const int lo16 = l & 15;

    short8 af[4];
    const int arow = w * 16 + lo16;
    #pragma unroll
    for (int kc = 0; kc < 4; ++kc)
        af[kc] = *(const short8*)&As[arow * 136 + kc * 32 + quad * 8];
    __syncthreads();    // As dead; LDS reused as transpose buffers

    f32x4 acc[16];
    #pragma unroll
    for (int nt = 0; nt < 16; ++nt) acc[nt] = (f32x4){0.f, 0.f, 0.f, 0.f};

    #pragma unroll 2
    for (int nt = 0; nt < 16; ++nt) {
        // fragment-major: 4 consecutive 1KB wave-loads (sequential stream)
        const unsigned short* bp = &Btf[(size_t)(nt * 4) * 512 + (l << 3)];
        short8 b0 = *(const short8*)&bp[0];
        short8 b1 = *(const short8*)&bp[512];
        short8 b2 = *(const short8*)&bp[1024];
        short8 b3 = *(const short8*)&bp[1536];
        acc[nt] = __builtin_amdgcn_mfma_f32_16x16x32_bf16(af[0], b0, acc[nt], 0, 0, 0);
        acc[nt] = __builtin_amdgcn_mfma_f32_16x16x32_bf16(af[1], b1, acc[nt], 0, 0, 0);
        acc[nt] = __builtin_amdgcn_mfma_f32_16x16x32_bf16(af[2], b2, acc[nt], 0, 0, 0);
        acc[nt] = __builtin_amdgcn_mfma_f32_16x16x32_bf16(af[3], b3, acc[nt], 0, 0, 0);
    }

    float* T = (float*)smem + w * 16 * 132;

    // pass 0: x columns (nt 0..7) + fused logits
    #pragma unroll
    for (int nt = 0; nt < 8; ++nt) {
        #pragma unroll
        for (int r = 0; r < 4; ++r)
            T[(quad * 4 + r) * 132 + nt * 16 + lo16] = acc[nt][r];
    }
    #pragma unroll
    for (int i = 0; i < 8; ++i) {
        int flat = i * 256 + l * 4;
        int row  = flat >> 7;
        int col  = flat & 127;
        float4 v = *(float4*)&T[row * 132 + col];
        int node = base + w * 16 + row;
        if (node < NN) {
            ushort4 h;
            h.x = f2bf(v.x); h.y = f2bf(v.y); h.z = f2bf(v.z); h.w = f2bf(v.w);
            *(ushort4*)&xb[(size_t)node * C + col] = h;
        }
        float4 ws = *(const float4*)&att_src[col];
        float4 wd = *(const float4*)&att_dst[col];
        float ps = v.x * ws.x + v.y * ws.y + v.z * ws.z + v.w * ws.w;
        float pd = v.x * wd.x + v.y * wd.y + v.z * wd.z + v.w * wd.w;
        #pragma unroll
        for (int d = 4; d > 0; d >>= 1) {
            ps += __shfl_down(ps, d, 64);
            pd += __shfl_down(pd, d, 64);
        }
        if ((l & 7) == 0 && node < NN) {
            int h = (l & 31) >> 3;
            a_s[node * 4 + h] = ps;
            a_d[node * 4 + h] = pd;
        }
    }

    // pass 1: out columns (nt 8..15), fp32
    #pragma unroll
    for (int nt = 8; nt < 16; ++nt) {
        #pragma unroll
        for (int r = 0; r < 4; ++r)
            T[(quad * 4 + r) * 132 + (nt - 8) * 16 + lo16] = acc[nt][r];
    }
    #pragma unroll
    for (int i = 0; i < 8; ++i) {
        int flat = i * 256 + l * 4;
        int row  = flat >> 7;
        int col  = flat & 127;
        float4 v = *(float4*)&T[row * 132 + col];
        int node = base + w * 16 + row;
        if (node < NN)
            *(float4*)&out[(size_t)node * C + col] = v;
    }
}

// ---------------------------------------------------------------------------
// hist: degree histogram + per-edge rank (atomicAdd return) so scatter is
// atomic-free.
// ---------------------------------------------------------------------------
__global__ void hist_kernel(const int* __restrict__ dst, int* __restrict__ deg,
                            int* __restrict__ rank)
{
    int e = blockIdx.x * blockDim.x + threadIdx.x;
    if (e < NE) rank[e] = atomicAdd(&deg[dst[e]], 1);
}

// ---------------------------------------------------------------------------
// multi-block exclusive scan
// ---------------------------------------------------------------------------
__global__ __launch_bounds__(1024)
void scan1_kernel(const int* __restrict__ deg, int* __restrict__ row_ptr,
                  int* __restrict__ bsum)
{
    __shared__ int wsum[16];
    const int t = threadIdx.x, lane = t & 63, wid = t >> 6;
    const int i = blockIdx.x * 1024 + t;
    int v0 = (i < NN) ? deg[i] : 0;
    int v = v0;
    #pragma unroll
    for (int off = 1; off < 64; off <<= 1) {
        int u = __shfl_up(v, off, 64);
        if (lane >= off) v += u;
    }
    if (lane == 63) wsum[wid] = v;
    __syncthreads();
    if (t == 0) {
        int run = 0;
        #pragma unroll
        for (int s = 0; s < 16; ++s) { int tmp = wsum[s]; wsum[s] = run; run += tmp; }
        bsum[blockIdx.x] = run;
    }
    __syncthreads();
    if (i < NN) row_ptr[i] = wsum[wid] + (v - v0);
}

__global__ __launch_bounds__(128)
void scan2_kernel(int* __restrict__ bsum)
{
    __shared__ int w0;
    const int t = threadIdx.x, lane = t & 63;
    int v0 = (t < SCAN_NB) ? bsum[t] : 0;
    int v = v0;
    #pragma unroll
    for (int off = 1; off < 64; off <<= 1) {
        int u = __shfl_up(v, off, 64);
        if (lane >= off) v += u;
    }
    if (t == 63) w0 = v;
    __syncthreads();
    int excl = (v - v0) + ((t >= 64) ? w0 : 0);
    if (t < SCAN_NB) bsum[t] = excl;
}

__global__ __launch_bounds__(1024)
void scan3_kernel(int* __restrict__ row_ptr, const int* __restrict__ bsum)
{
    const int i = blockIdx.x * 1024 + threadIdx.x;
    if (i < NN) row_ptr[i] = row_ptr[i] + bsum[i >> 10];
    if (i == 0) row_ptr[NN] = NE;
}

// ---------------------------------------------------------------------------
// scatter: pure load->store, no atomics
// ---------------------------------------------------------------------------
__global__ void scatter_kernel(const int* __restrict__ src,
                               const int* __restrict__ dst,
                               const int* __restrict__ rank,
                               const int* __restrict__ row_ptr,
                               int* __restrict__ csr_src)
{
    int e = blockIdx.x * blockDim.x + threadIdx.x;
    if (e < NE)
        csr_src[row_ptr[dst[e]] + rank[e]] = src[e];
}

// ---------------------------------------------------------------------------
// aggregation: one wave per dst node, single pass (unchanged from round 4)
// ---------------------------------------------------------------------------
__global__ __launch_bounds__(256)
void agg_kernel(const unsigned short* __restrict__ xb,
                const float* __restrict__ a_s,
                const float* __restrict__ a_d,
                const int* __restrict__ row_ptr,
                const int* __restrict__ csr_src,
                float* __restrict__ out)
{
    __shared__ float s_alpha[4][64 * 4];
    __shared__ int   s_srcs[4][64];
    const int tid = threadIdx.x;
    const int w = tid >> 6;
    const int l = tid & 63;
    const int n = blockIdx.x * 4 + w;
    if (n >= NN) return;
    const int r0  = row_ptr[n];
    const int deg = row_ptr[n + 1] - r0;
    if (deg == 0) return;

    const float4 ad4 = *(const float4*)&a_d[n * 4];
    const int half = l >> 5;
    const int hl   = l & 31;
    const int h    = hl >> 3;

    float ax = 0.f, ay = 0.f, az = 0.f, aw = 0.f;
    float dx = 0.f, dy = 0.f, dz = 0.f, dw = 0.f;

    for (int c0 = 0; c0 < deg; c0 += 64) {
        int e = c0 + l;
        int s = 0;
        float4 ex = {0.f, 0.f, 0.f, 0.f};
        if (e < deg) {
            s = csr_src[r0 + e];
            float4 as4 = *(const float4*)&a_s[s * 4];
            float e0 = as4.x + ad4.x, e1 = as4.y + ad4.y;
            float e2 = as4.z + ad4.z, e3 = as4.w + ad4.w;
            e0 = (e0 > 0.f) ? e0 : NEG_SLOPE * e0;
            e1 = (e1 > 0.f) ? e1 : NEG_SLOPE * e1;
            e2 = (e2 > 0.f) ? e2 : NEG_SLOPE * e2;
            e3 = (e3 > 0.f) ? e3 : NEG_SLOPE * e3;
            ex.x = __expf(e0); ex.y = __expf(e1);
            ex.z = __expf(e2); ex.w = __expf(e3);
            dx += ex.x; dy += ex.y; dz += ex.z; dw += ex.w;
        }
        s_srcs[w][l] = s;
        *(float4*)&s_alpha[w][l * 4] = ex;

        int cn = min(64, deg - c0);
        int iters = (cn + 1) >> 1;
        #pragma unroll 2
        for (int i = 0; i < iters; ++i) {
            int ii = i * 2 + half;
            int   si = s_srcs[w][ii];
            float al = s_alpha[w][ii * 4 + h];
            ushort4 uv = *(const ushort4*)&xb[(size_t)si * C + hl * 4];
            ax = fmaf(al, bf2f(uv.x), ax);
            ay = fmaf(al, bf2f(uv.y), ay);
            az = fmaf(al, bf2f(uv.z), az);
            aw = fmaf(al, bf2f(uv.w), aw);
        }
    }

    #pragma unroll
    for (int d = 32; d > 0; d >>= 1) {
        dx += __shfl_xor(dx, d, 64);
        dy += __shfl_xor(dy, d, 64);
        dz += __shfl_xor(dz, d, 64);
        dw += __shfl_xor(dw, d, 64);
    }
    float den = (h == 0) ? dx : (h == 1) ? dy : (h == 2) ? dz : dw;
    float inv = 1.f / den;

    ax += __shfl_xor(ax, 32, 64);
    ay += __shfl_xor(ay, 32, 64);
    az += __shfl_xor(az, 32, 64);
    aw += __shfl_xor(aw, 32, 64);

    if (half == 0) {
        float4 o = *(float4*)&out[(size_t)n * C + hl * 4];
        o.x += ax * inv; o.y += ay * inv; o.z += az * inv; o.w += aw * inv;
        *(float4*)&out[(size_t)n * C + hl * 4] = o;
    }
}

// ---------------------------------------------------------------------------
extern "C" void kernel_launch(void* const* d_in, const int* in_sizes, int n_in,
                              void* d_out, int out_size, void* d_ws, size_t ws_size,
                              hipStream_t stream)
{
    const float* feat    = (const float*)d_in[0];
    const float* W       = (const float*)d_in[1];
    const float* att_src = (const float*)d_in[2];
    const float* att_dst = (const float*)d_in[3];
    const float* W_res   = (const float*)d_in[4];
    const int*   src     = (const int*)d_in[5];
    const int*   dst     = (const int*)d_in[6];
    float* out = (float*)d_out;

    char* p = (char*)d_ws;
    unsigned short* xb  = (unsigned short*)p; p += (size_t)NN * C * sizeof(unsigned short);
    unsigned short* Btf = (unsigned short*)p; p += (size_t)256 * 128 * sizeof(unsigned short);
    float* a_s = (float*)p;            p += (size_t)NN * 4 * sizeof(float);
    float* a_d = (float*)p;            p += (size_t)NN * 4 * sizeof(float);
    int* deg     = (int*)p;            p += (size_t)NN * sizeof(int);
    int* row_ptr = (int*)p;            p += (size_t)(NN + 1) * sizeof(int);
    int* bsum    = (int*)p;            p += (size_t)256 * sizeof(int);
    int* rank    = (int*)p;            p += (size_t)NE * sizeof(int);
    int* csr_src = (int*)p;            p += (size_t)NE * sizeof(int);

    hipMemsetAsync(deg, 0, (size_t)NN * sizeof(int), stream);

    wconv_kernel<<<16, 256, 0, stream>>>(W, W_res, Btf);
    proj_mfma<<<(NN + 63) / 64, 256, 0, stream>>>(feat, Btf, att_src, att_dst,
                                                  xb, a_s, a_d, out);
    hist_kernel<<<(NE + 255) / 256, 256, 0, stream>>>(dst, deg, rank);
    scan1_kernel<<<SCAN_NB, 1024, 0, stream>>>(deg, row_ptr, bsum);
    scan2_kernel<<<1, 128, 0, stream>>>(bsum);
    scan3_kernel<<<SCAN_NB, 1024, 0, stream>>>(row_ptr, bsum);
    scatter_kernel<<<(NE + 255) / 256, 256, 0, stream>>>(src, dst, rank, row_ptr, csr_src);
    agg_kernel<<<(NN + 3) / 4, 256, 0, stream>>>(xb, a_s, a_d, row_ptr, csr_src, out);
}

// Round 6
// 368.798 us; speedup vs baseline: 1.9595x; 1.1038x over previous
//
#include <hip/hip_runtime.h>
#include <math.h>

#define NN 100000
#define NE 1600000
#define F_IN 128
#define C 128           // N_HEADS * F_OUT
#define NEG_SLOPE 0.2f
#define SCAN_NB ((NN + 1023) / 1024)   // 98
#define PROJ_NB ((NN + 63) / 64)       // 1563
#define HIST_NB ((NE + 255) / 256)     // 6250

typedef __attribute__((ext_vector_type(8))) short short8;    // 8 x bf16
typedef __attribute__((ext_vector_type(4))) float f32x4;
typedef __attribute__((ext_vector_type(4))) float floatx4;
typedef __attribute__((ext_vector_type(4))) unsigned short ushortx4;

static __device__ __forceinline__ unsigned short f2bf(float f) {
    unsigned int u = __float_as_uint(f);
    unsigned int r = (u + 0x7fff + ((u >> 16) & 1)) >> 16;  // RNE
    return (unsigned short)r;
}
static __device__ __forceinline__ float bf2f(unsigned short h) {
    return __uint_as_float((unsigned int)h << 16);
}

// ---------------------------------------------------------------------------
// Btf: fragment-major B for mfma_f32_16x16x32_bf16 (as round 5).
// Btf[((nt*4+kc)*64 + lane)*8 + j] = B[k][n], n = nt*16+(lane&15),
//   k = kc*32 + (lane>>4)*8 + j.  n<128 -> W, else W_res.
// ---------------------------------------------------------------------------
__global__ __launch_bounds__(256)
void wconv_kernel(const float* __restrict__ W,
                  const float* __restrict__ Wr,
                  unsigned short* __restrict__ Btf)
{
    int g = blockIdx.x * 256 + threadIdx.x;   // 0..4095
    int nt = g >> 8;
    int kc = (g >> 6) & 3;
    int l  = g & 63;
    int n  = nt * 16 + (l & 15);
    int kb = kc * 32 + (l >> 4) * 8;
    unsigned short v[8];
    #pragma unroll
    for (int j = 0; j < 8; ++j) {
        int k = kb + j;
        float f = (n < 128) ? W[(size_t)k * 128 + n] : Wr[(size_t)k * 128 + (n - 128)];
        v[j] = f2bf(f);
    }
    *(short8*)&Btf[(size_t)g * 8] = *(short8*)v;
}

// ---------------------------------------------------------------------------
// Fat kernel: blocks [0,PROJ_NB) = projection GEMM; blocks >= PROJ_NB = edge
// histogram (atomic-latency-bound, hides under the GEMM).
// proj: x(bf16 nt-store), res(fp32 nt-store)->out, fused logits.
// LDS = 17408B: A-stage [64][136] bf16; each wave's T half-tile [16][68] f32
// exactly overlays its OWN A rows (wave-private, DS in-order => no barrier).
// ---------------------------------------------------------------------------
__global__ __launch_bounds__(256)
void proj_hist_kernel(const float* __restrict__ feat,
                      const unsigned short* __restrict__ Btf,
                      const float* __restrict__ att_src,
                      const float* __restrict__ att_dst,
                      const int* __restrict__ dst,
                      unsigned short* __restrict__ xb,
                      float* __restrict__ a_s,
                      float* __restrict__ a_d,
                      float* __restrict__ out,
                      int* __restrict__ deg,
                      int* __restrict__ rank)
{
    __shared__ __align__(16) char smem[17408];
    const int tid = threadIdx.x;

    if (blockIdx.x >= PROJ_NB) {          // ---- histogram part ----
        int e = (blockIdx.x - PROJ_NB) * 256 + tid;
        if (e < NE) rank[e] = atomicAdd(&deg[dst[e]], 1);
        return;
    }

    unsigned short* As = (unsigned short*)smem;   // [64][136]
    const int base = blockIdx.x * 64;

    #pragma unroll
    for (int it = 0; it < 8; ++it) {
        int idx = it * 256 + tid;
        int row = idx >> 5;
        int c4  = idx & 31;
        int n = base + row;
        if (n < NN) {
            floatx4 f = __builtin_nontemporal_load(
                (const floatx4*)&feat[(size_t)n * F_IN + c4 * 4]);
            ushortx4 h;
            h.x = f2bf(f.x); h.y = f2bf(f.y); h.z = f2bf(f.z); h.w = f2bf(f.w);
            *(ushortx4*)&As[row * 136 + c4 * 4] = h;
        }
    }
    __syncthreads();

    const int l = tid & 63;
    const int w = tid >> 6;
    const int quad = l >> 4;
    const int lo16 = l & 15;

    short8 af[4];
    const int arow = w * 16 + lo16;
    #pragma unroll
    for (int kc = 0; kc < 4; ++kc)
        af[kc] = *(const short8*)&As[arow * 136 + kc * 32 + quad * 8];
    // No barrier needed: each wave's T region == its own A rows.

    f32x4 acc[16];
    #pragma unroll
    for (int nt = 0; nt < 16; ++nt) acc[nt] = (f32x4){0.f, 0.f, 0.f, 0.f};

    #pragma unroll 2
    for (int nt = 0; nt < 16; ++nt) {
        const unsigned short* bp = &Btf[(size_t)(nt * 4) * 512 + (l << 3)];
        short8 b0 = *(const short8*)&bp[0];
        short8 b1 = *(const short8*)&bp[512];
        short8 b2 = *(const short8*)&bp[1024];
        short8 b3 = *(const short8*)&bp[1536];
        acc[nt] = __builtin_amdgcn_mfma_f32_16x16x32_bf16(af[0], b0, acc[nt], 0, 0, 0);
        acc[nt] = __builtin_amdgcn_mfma_f32_16x16x32_bf16(af[1], b1, acc[nt], 0, 0, 0);
        acc[nt] = __builtin_amdgcn_mfma_f32_16x16x32_bf16(af[2], b2, acc[nt], 0, 0, 0);
        acc[nt] = __builtin_amdgcn_mfma_f32_16x16x32_bf16(af[3], b3, acc[nt], 0, 0, 0);
    }

    float* T2 = (float*)smem + w * (16 * 68);   // wave-private [16][68]
    const int g  = l >> 4;          // row group within half-tile read
    const int cf = (l & 15) * 4;    // col (0..60) within 64-col half

    // ---- x passes (nt 0..7) + fused logits ----
    #pragma unroll
    for (int p = 0; p < 2; ++p) {
        #pragma unroll
        for (int ntl = 0; ntl < 4; ++ntl) {
            int nt = p * 4 + ntl;
            #pragma unroll
            for (int r = 0; r < 4; ++r)
                T2[(quad * 4 + r) * 68 + ntl * 16 + lo16] = acc[nt][r];
        }
        floatx4 ws4 = *(const floatx4*)&att_src[p * 64 + cf];
        floatx4 wd4 = *(const floatx4*)&att_dst[p * 64 + cf];
        float ps[4], pd[4];
        #pragma unroll
        for (int it = 0; it < 4; ++it) {
            int row = it * 4 + g;
            floatx4 v = *(floatx4*)&T2[row * 68 + cf];
            int node = base + w * 16 + row;
            ushortx4 hh;
            hh.x = f2bf(v.x); hh.y = f2bf(v.y); hh.z = f2bf(v.z); hh.w = f2bf(v.w);
            if (node < NN)
                __builtin_nontemporal_store(hh,
                    (ushortx4*)&xb[(size_t)node * C + p * 64 + cf]);
            ps[it] = v.x * ws4.x + v.y * ws4.y + v.z * ws4.z + v.w * ws4.w;
            pd[it] = v.x * wd4.x + v.y * wd4.y + v.z * wd4.z + v.w * wd4.w;
        }
        #pragma unroll
        for (int it = 0; it < 4; ++it) {
            #pragma unroll
            for (int d = 1; d < 8; d <<= 1) {
                ps[it] += __shfl_xor(ps[it], d, 64);
                pd[it] += __shfl_xor(pd[it], d, 64);
            }
        }
        if ((l & 7) == 0) {
            int hh = p * 2 + ((l & 15) >> 3);
            #pragma unroll
            for (int it = 0; it < 4; ++it) {
                int node = base + w * 16 + it * 4 + g;
                if (node < NN) {
                    a_s[node * 4 + hh] = ps[it];
                    a_d[node * 4 + hh] = pd[it];
                }
            }
        }
    }

    // ---- out passes (nt 8..15), fp32 ----
    #pragma unroll
    for (int p = 0; p < 2; ++p) {
        #pragma unroll
        for (int ntl = 0; ntl < 4; ++ntl) {
            int nt = 8 + p * 4 + ntl;
            #pragma unroll
            for (int r = 0; r < 4; ++r)
                T2[(quad * 4 + r) * 68 + ntl * 16 + lo16] = acc[nt][r];
        }
        #pragma unroll
        for (int it = 0; it < 4; ++it) {
            int row = it * 4 + g;
            floatx4 v = *(floatx4*)&T2[row * 68 + cf];
            int node = base + w * 16 + row;
            if (node < NN)
                __builtin_nontemporal_store(v,
                    (floatx4*)&out[(size_t)node * C + p * 64 + cf]);
        }
    }
}

// ---------------------------------------------------------------------------
// multi-block exclusive scan
// ---------------------------------------------------------------------------
__global__ __launch_bounds__(1024)
void scan1_kernel(const int* __restrict__ deg, int* __restrict__ row_ptr,
                  int* __restrict__ bsum)
{
    __shared__ int wsum[16];
    const int t = threadIdx.x, lane = t & 63, wid = t >> 6;
    const int i = blockIdx.x * 1024 + t;
    int v0 = (i < NN) ? deg[i] : 0;
    int v = v0;
    #pragma unroll
    for (int off = 1; off < 64; off <<= 1) {
        int u = __shfl_up(v, off, 64);
        if (lane >= off) v += u;
    }
    if (lane == 63) wsum[wid] = v;
    __syncthreads();
    if (t == 0) {
        int run = 0;
        #pragma unroll
        for (int s = 0; s < 16; ++s) { int tmp = wsum[s]; wsum[s] = run; run += tmp; }
        bsum[blockIdx.x] = run;
    }
    __syncthreads();
    if (i < NN) row_ptr[i] = wsum[wid] + (v - v0);
}

__global__ __launch_bounds__(128)
void scan2_kernel(int* __restrict__ bsum)
{
    __shared__ int w0;
    const int t = threadIdx.x, lane = t & 63;
    int v0 = (t < SCAN_NB) ? bsum[t] : 0;
    int v = v0;
    #pragma unroll
    for (int off = 1; off < 64; off <<= 1) {
        int u = __shfl_up(v, off, 64);
        if (lane >= off) v += u;
    }
    if (t == 63) w0 = v;
    __syncthreads();
    int excl = (v - v0) + ((t >= 64) ? w0 : 0);
    if (t < SCAN_NB) bsum[t] = excl;
}

__global__ __launch_bounds__(1024)
void scan3_kernel(int* __restrict__ row_ptr, const int* __restrict__ bsum)
{
    const int i = blockIdx.x * 1024 + threadIdx.x;
    if (i < NN) row_ptr[i] = row_ptr[i] + bsum[i >> 10];
    if (i == 0) row_ptr[NN] = NE;
}

// ---------------------------------------------------------------------------
// scatter: pure load->store, no atomics
// ---------------------------------------------------------------------------
__global__ void scatter_kernel(const int* __restrict__ src,
                               const int* __restrict__ dst,
                               const int* __restrict__ rank,
                               const int* __restrict__ row_ptr,
                               int* __restrict__ csr_src)
{
    int e = blockIdx.x * blockDim.x + threadIdx.x;
    if (e < NE)
        csr_src[row_ptr[dst[e]] + rank[e]] = src[e];
}

// ---------------------------------------------------------------------------
// aggregation: one wave per dst node, single pass (unchanged from round 4)
// ---------------------------------------------------------------------------
__global__ __launch_bounds__(256)
void agg_kernel(const unsigned short* __restrict__ xb,
                const float* __restrict__ a_s,
                const float* __restrict__ a_d,
                const int* __restrict__ row_ptr,
                const int* __restrict__ csr_src,
                float* __restrict__ out)
{
    __shared__ float s_alpha[4][64 * 4];
    __shared__ int   s_srcs[4][64];
    const int tid = threadIdx.x;
    const int w = tid >> 6;
    const int l = tid & 63;
    const int n = blockIdx.x * 4 + w;
    if (n >= NN) return;
    const int r0  = row_ptr[n];
    const int deg = row_ptr[n + 1] - r0;
    if (deg == 0) return;

    const float4 ad4 = *(const float4*)&a_d[n * 4];
    const int half = l >> 5;
    const int hl   = l & 31;
    const int h    = hl >> 3;

    float ax = 0.f, ay = 0.f, az = 0.f, aw = 0.f;
    float dx = 0.f, dy = 0.f, dz = 0.f, dw = 0.f;

    for (int c0 = 0; c0 < deg; c0 += 64) {
        int e = c0 + l;
        int s = 0;
        float4 ex = {0.f, 0.f, 0.f, 0.f};
        if (e < deg) {
            s = csr_src[r0 + e];
            float4 as4 = *(const float4*)&a_s[s * 4];
            float e0 = as4.x + ad4.x, e1 = as4.y + ad4.y;
            float e2 = as4.z + ad4.z, e3 = as4.w + ad4.w;
            e0 = (e0 > 0.f) ? e0 : NEG_SLOPE * e0;
            e1 = (e1 > 0.f) ? e1 : NEG_SLOPE * e1;
            e2 = (e2 > 0.f) ? e2 : NEG_SLOPE * e2;
            e3 = (e3 > 0.f) ? e3 : NEG_SLOPE * e3;
            ex.x = __expf(e0); ex.y = __expf(e1);
            ex.z = __expf(e2); ex.w = __expf(e3);
            dx += ex.x; dy += ex.y; dz += ex.z; dw += ex.w;
        }
        s_srcs[w][l] = s;
        *(float4*)&s_alpha[w][l * 4] = ex;

        int cn = min(64, deg - c0);
        int iters = (cn + 1) >> 1;
        #pragma unroll 2
        for (int i = 0; i < iters; ++i) {
            int ii = i * 2 + half;
            int   si = s_srcs[w][ii];
            float al = s_alpha[w][ii * 4 + h];
            ushort4 uv = *(const ushort4*)&xb[(size_t)si * C + hl * 4];
            ax = fmaf(al, bf2f(uv.x), ax);
            ay = fmaf(al, bf2f(uv.y), ay);
            az = fmaf(al, bf2f(uv.z), az);
            aw = fmaf(al, bf2f(uv.w), aw);
        }
    }

    #pragma unroll
    for (int d = 32; d > 0; d >>= 1) {
        dx += __shfl_xor(dx, d, 64);
        dy += __shfl_xor(dy, d, 64);
        dz += __shfl_xor(dz, d, 64);
        dw += __shfl_xor(dw, d, 64);
    }
    float den = (h == 0) ? dx : (h == 1) ? dy : (h == 2) ? dz : dw;
    float inv = 1.f / den;

    ax += __shfl_xor(ax, 32, 64);
    ay += __shfl_xor(ay, 32, 64);
    az += __shfl_xor(az, 32, 64);
    aw += __shfl_xor(aw, 32, 64);

    if (half == 0) {
        float4 o = *(float4*)&out[(size_t)n * C + hl * 4];
        o.x += ax * inv; o.y += ay * inv; o.z += az * inv; o.w += aw * inv;
        *(float4*)&out[(size_t)n * C + hl * 4] = o;
    }
}

// ---------------------------------------------------------------------------
extern "C" void kernel_launch(void* const* d_in, const int* in_sizes, int n_in,
                              void* d_out, int out_size, void* d_ws, size_t ws_size,
                              hipStream_t stream)
{
    const float* feat    = (const float*)d_in[0];
    const float* W       = (const float*)d_in[1];
    const float* att_src = (const float*)d_in[2];
    const float* att_dst = (const float*)d_in[3];
    const float* W_res   = (const float*)d_in[4];
    const int*   src     = (const int*)d_in[5];
    const int*   dst     = (const int*)d_in[6];
    float* out = (float*)d_out;

    char* p = (char*)d_ws;
    unsigned short* xb  = (unsigned short*)p; p += (size_t)NN * C * sizeof(unsigned short);
    unsigned short* Btf = (unsigned short*)p; p += (size_t)256 * 128 * sizeof(unsigned short);
    float* a_s = (float*)p;            p += (size_t)NN * 4 * sizeof(float);
    float* a_d = (float*)p;            p += (size_t)NN * 4 * sizeof(float);
    int* deg     = (int*)p;            p += (size_t)NN * sizeof(int);
    int* row_ptr = (int*)p;            p += (size_t)(NN + 1) * sizeof(int);
    int* bsum    = (int*)p;            p += (size_t)256 * sizeof(int);
    int* rank    = (int*)p;            p += (size_t)NE * sizeof(int);
    int* csr_src = (int*)p;            p += (size_t)NE * sizeof(int);

    hipMemsetAsync(deg, 0, (size_t)NN * sizeof(int), stream);

    wconv_kernel<<<16, 256, 0, stream>>>(W, W_res, Btf);
    proj_hist_kernel<<<PROJ_NB + HIST_NB, 256, 0, stream>>>(
        feat, Btf, att_src, att_dst, dst, xb, a_s, a_d, out, deg, rank);
    scan1_kernel<<<SCAN_NB, 1024, 0, stream>>>(deg, row_ptr, bsum);
    scan2_kernel<<<1, 128, 0, stream>>>(bsum);
    scan3_kernel<<<SCAN_NB, 1024, 0, stream>>>(row_ptr, bsum);
    scatter_kernel<<<(NE + 255) / 256, 256, 0, stream>>>(src, dst, rank, row_ptr, csr_src);
    agg_kernel<<<(NN + 3) / 4, 256, 0, stream>>>(xb, a_s, a_d, row_ptr, csr_src, out);
}